// Round 15
// baseline (55.574 us; speedup 1.0000x reference)
//
#include <hip/hip_runtime.h>
#include <stdint.h>

#define B_ 4
#define S_ 4096
#define D_ 128
#define KVB 64
#define NT (S_ / KVB)
#define NR (B_ * S_)

typedef __bf16 bf16;
typedef __bf16 bf16x8 __attribute__((ext_vector_type(8)));
typedef float f32x4 __attribute__((ext_vector_type(4)));
typedef float f32x16 __attribute__((ext_vector_type(16)));

// ws layout (bytes)
#define QB_OFF  0
#define KB_OFF  (QB_OFF + B_*S_*D_*2)
#define VTB_OFF (KB_OFF + B_*S_*D_*2)
#define ACC_OFF (VTB_OFF + B_*S_*D_*2)          // 12582912

#define GLOAD_LDS16(g, l)                                                    \
  __builtin_amdgcn_global_load_lds(                                          \
      (const __attribute__((address_space(1))) void*)(g),                    \
      (__attribute__((address_space(3))) void*)(l), 16, 0, 0)

// ------------------------------------------------- QKV projection (bf16 MFMA)
// grid (256, 3): blockIdx.y = matrix (0=Q,1=K,2=V). W converted fp32->bf16
// into swizzled LDS per block. Q PRE-SCALED by log2e/128 (attn softmax is
// bare exp2). V transposed [B][D][S] and kappa-16 interleaved: within each
// 16-kv block, position p = h*8+j holds kv = (j>>2)*8 + h*4 + (j&3) — the
// order that makes attn's 32x32 PV A-frag pack the identity on S^T regs.
__global__ __launch_bounds__(256) void proj_kernel(const float* __restrict__ x,
    const float* __restrict__ wq, const float* __restrict__ wk,
    const float* __restrict__ wv, bf16* __restrict__ qb, bf16* __restrict__ kb,
    bf16* __restrict__ vtb) {
  __shared__ bf16 ct[64][136];                       // 17.4 KB (C staging)
  __shared__ __align__(16) bf16 wl[128 * 128];       // 32 KB swizzled W
  const int tid  = threadIdx.x;
  const int wave = tid >> 6, lane = tid & 63;
  const int lrow = lane & 15, g = lane >> 4;
  const int m = blockIdx.y;
  const float* w = (m == 0) ? wq : (m == 1 ? wk : wv);
  const int row0b = blockIdx.x * 64;
  const int row0  = row0b + wave * 16;
  const float SC = 1.4426950408889634f / 128.0f;     // log2(e)/D

  // ---- W fp32 -> bf16 into swizzled LDS (2048 chunks of 16B, 8/thread)
#pragma unroll
  for (int it = 0; it < 8; ++it) {
    int chv = it * 256 + tid;                        // 0..2047
    int row = chv >> 4, pos = chv & 15;
    const float4* wp = (const float4*)(w + (size_t)chv * 8);
    float4 w0 = wp[0], w1 = wp[1];
    bf16x8 v;
    v[0]=(bf16)w0.x; v[1]=(bf16)w0.y; v[2]=(bf16)w0.z; v[3]=(bf16)w0.w;
    v[4]=(bf16)w1.x; v[5]=(bf16)w1.y; v[6]=(bf16)w1.z; v[7]=(bf16)w1.w;
    *(bf16x8*)(&wl[row * 128 + ((pos ^ (row & 15)) * 8)]) = v;
  }

  bf16x8 af[4];
  {
    const float* xp = x + (size_t)(row0 + lrow) * D_ + g * 8;
#pragma unroll
    for (int ks = 0; ks < 4; ++ks) {
      const float4* p4 = (const float4*)(xp + ks * 32);
      float4 a0 = p4[0], a1 = p4[1];
      bf16x8 v;
      v[0]=(bf16)a0.x; v[1]=(bf16)a0.y; v[2]=(bf16)a0.z; v[3]=(bf16)a0.w;
      v[4]=(bf16)a1.x; v[5]=(bf16)a1.y; v[6]=(bf16)a1.z; v[7]=(bf16)a1.w;
      af[ks] = v;
    }
  }
  __syncthreads();                                   // wl ready

  f32x4 acc[8];
#pragma unroll
  for (int c = 0; c < 8; ++c) acc[c] = (f32x4){0.f, 0.f, 0.f, 0.f};
#pragma unroll
  for (int c = 0; c < 8; ++c) {
#pragma unroll
    for (int ks = 0; ks < 4; ++ks) {
      bf16x8 bf = *(const bf16x8*)(
          &wl[(c * 16 + lrow) * 128 + (((ks * 4 + g) ^ lrow) * 8)]);
      acc[c] = __builtin_amdgcn_mfma_f32_16x16x32_bf16(af[ks], bf, acc[c], 0, 0, 0);
    }
  }
  const float osc = (m == 0) ? SC : 1.0f;            // pre-scale Q only
#pragma unroll
  for (int c = 0; c < 8; ++c)
#pragma unroll
    for (int r = 0; r < 4; ++r)
      ct[wave * 16 + g * 4 + r][c * 16 + lrow] = (bf16)(acc[c][r] * osc);
  __syncthreads();

  if (m < 2) {
    bf16* ob = (m == 0) ? qb : kb;
#pragma unroll
    for (int it = 0; it < 4; ++it) {
      int chunk = it * 256 + tid;
      int row = chunk >> 4, pos = chunk & 15;
      *(bf16x8*)(ob + (size_t)(row0b + row) * D_ + pos * 8) =
          *(const bf16x8*)(&ct[row][pos * 8]);
    }
  } else {
    const int b = row0b / S_;
    const int sb = row0b & (S_ - 1);
#pragma unroll
    for (int it = 0; it < 4; ++it) {
      int ci = it * 256 + tid;                       // 1024 chunks
      int e = ci >> 3, c8 = ci & 7;                  // c8: which 8-kv chunk
      int h2 = c8 & 1, blk = c8 >> 1;                // 16-kv block, half
      bf16x8 v;
#pragma unroll
      for (int j = 0; j < 8; ++j)
        v[j] = ct[blk * 16 + (j >> 2) * 8 + h2 * 4 + (j & 3)][e];
      *(bf16x8*)(vtb + (size_t)(b * D_ + e) * S_ + sb + c8 * 8) = v;
    }
  }
}

// ------------------------------------------------------------ flash attention
// 32x32x16 MFMA core (half the MFMA instructions of 16x16, +15% pipe ceiling).
// 1D grid (128*ns), XCD-swizzled, 4 waves x 32 q-rows, KVB=64, 2-deep LDS
// buffers, ONE vmcnt(0)+barrier per tile (R13 schedule).
// S^T = mfma32(A=K,B=Q): lane holds S[q=lane&31][kv=(reg&3)+8(reg>>2)+4h].
// PV = mfma32(A=P,B=V^T): kappa-16-stored V makes the P pack identity:
// pa0=s[0..7], pa1=s[8..15] per kv-32 tile. 4-phase interleave hides exp2
// under MFMA issue: QK0 | QK1+exp(s0) | PVa+exp(s1) | PVb.
// K LDS: 64 rows x 256B, 16-slot XOR (row&15). V LDS: paired d-rows in 256B
// stripes, 16-slot XOR (stripe&15) — per-16-lane-phase conflict-free.
__global__ __launch_bounds__(256, 2) void attn_kernel(const bf16* __restrict__ qb,
    const bf16* __restrict__ kb, const bf16* __restrict__ vtb,
    float* __restrict__ out, bf16* __restrict__ accP, float* __restrict__ lP,
    int ns) {
  __shared__ __align__(16) bf16 Kt[2][KVB * 128];    // 2 x 16KB
  __shared__ __align__(16) bf16 Vt[2][64 * 128];     // 2 x 16KB (64 stripes)

  const int tid  = threadIdx.x;
  const int wave = tid >> 6, lane = tid & 63;
  const int l31 = lane & 31, h = lane >> 5;

  // bijective XCD swizzle (gridDim.x % 8 == 0 for ns in {1,2,4})
  const int nwg = gridDim.x;
  int gid = blockIdx.x;
  if ((nwg & 7) == 0) gid = (gid & 7) * (nwg >> 3) + (gid >> 3);
  const int qp  = gid & 127;                         // q-part 0..127
  const int seg = gid >> 7;                          // 0..ns-1
  const int b   = qp >> 5;
  const int q0  = (qp & 31) * 128 + wave * 32;       // wave's 32 q-rows

  // uneven tile ranges
  const int base = NT / ns, ext = NT % ns;
  const int cnt  = base + (seg < ext);
  const int t0   = seg * base + (seg < ext ? seg : ext);
  const int tend = t0 + cnt;

  // ---- staging offsets (lane-constant): 4 K-chunks + 4 V-chunks per lane
  int koff[4], voff[4], kd[4];
#pragma unroll
  for (int it = 0; it < 4; ++it) {
    int ci = (wave * 4 + it) * 64 + lane;            // 0..1023
    int krow = ci >> 4, kch = (ci & 15) ^ (krow & 15);
    koff[it] = krow * D_ + kch * 8;
    int u = ci >> 4, inner = (ci & 15) ^ (u & 15);
    int vd = u * 2 + (inner >> 3), vp8 = inner & 7;
    voff[it] = vd * S_ + vp8 * 8;
    kd[it] = (wave * 4 + it) * 512;                  // uniform dest (bf16 idx)
  }
  // K-read bases: row = kvt*32 + l31, chunk = (ks*2+h) ^ (l31&15)
  const int krb0 = l31 * 128;                        // kvt0 row base (bf16)
  const int krb1 = (32 + l31) * 128;                 // kvt1
  const int kx = l31 & 15;
  // V-read: stripe u = dt*16 + (l31>>1); chunk = ((lane&1)*8 + p8) ^ (l31>>1)
  const int vrb = (l31 >> 1) * 128;
  const int vx = l31 >> 1;
  const int ib = (lane & 1) * 8;

  // Q fragments: q = q0 + l31, k-chunk = ks*16 + h*8
  bf16x8 qf[8];
  {
    const bf16* qp_ = qb + (size_t)(b * S_ + q0 + l31) * D_ + h * 8;
#pragma unroll
    for (int ks = 0; ks < 8; ++ks) qf[ks] = *(const bf16x8*)(qp_ + ks * 16);
  }

  f32x16 acc[4];
#pragma unroll
  for (int dt = 0; dt < 4; ++dt)
#pragma unroll
    for (int i = 0; i < 16; ++i) acc[dt][i] = 0.f;
  float l_r = 0.f;                                   // per-lane l[q=l31] partial

  const bf16* kbase = kb + (size_t)b * S_ * D_;
  const bf16* vbase = vtb + (size_t)b * D_ * S_;

#define STAGE(tt, buf)                                                       \
  { const bf16* kp_ = kbase + (size_t)(tt) * KVB * D_;                       \
    const bf16* vp_ = vbase + (tt) * KVB;                                    \
    GLOAD_LDS16(kp_ + koff[0], &Kt[buf][kd[0]]);                             \
    GLOAD_LDS16(kp_ + koff[1], &Kt[buf][kd[1]]);                             \
    GLOAD_LDS16(kp_ + koff[2], &Kt[buf][kd[2]]);                             \
    GLOAD_LDS16(kp_ + koff[3], &Kt[buf][kd[3]]);                             \
    GLOAD_LDS16(vp_ + voff[0], &Vt[buf][kd[0]]);                             \
    GLOAD_LDS16(vp_ + voff[1], &Vt[buf][kd[1]]);                             \
    GLOAD_LDS16(vp_ + voff[2], &Vt[buf][kd[2]]);                             \
    GLOAD_LDS16(vp_ + voff[3], &Vt[buf][kd[3]]); }

  STAGE(t0, 0);                                      // prologue

  for (int t = t0; t < tend; ++t) {
    const int bcur = (t - t0) & 1;
    asm volatile("s_waitcnt vmcnt(0)\n\ts_barrier" ::: "memory");
    if (t + 1 < tend) STAGE(t + 1, bcur ^ 1);

    // ---- Phase A: QK kvt0 (8 mfma, chained)
    f32x16 s0, s1;
#pragma unroll
    for (int i = 0; i < 16; ++i) { s0[i] = 0.f; s1[i] = 0.f; }
#pragma unroll
    for (int ks = 0; ks < 8; ++ks) {
      bf16x8 kf = *(const bf16x8*)(&Kt[bcur][krb0 + (((ks * 2 + h) ^ kx) * 8)]);
      s0 = __builtin_amdgcn_mfma_f32_32x32x16_bf16(kf, qf[ks], s0, 0, 0, 0);
    }

    // ---- Phase B: QK kvt1 with exp(s0) interleaved
    float la = 0.f;
    bf16x8 pa0, pa1, pa2, pa3;
#pragma unroll
    for (int ks = 0; ks < 8; ++ks) {
      bf16x8 kf = *(const bf16x8*)(&Kt[bcur][krb1 + (((ks * 2 + h) ^ kx) * 8)]);
      s1 = __builtin_amdgcn_mfma_f32_32x32x16_bf16(kf, qf[ks], s1, 0, 0, 0);
      float e0 = __builtin_amdgcn_exp2f(s0[ks]);
      float e1 = __builtin_amdgcn_exp2f(s0[ks + 8]);
      la += e0 + e1;
      pa0[ks] = (bf16)e0;
      pa1[ks] = (bf16)e1;
    }

    // ---- Phase C: PV k-steps 0,1 (kvt0) with exp(s1) interleaved
    __builtin_amdgcn_s_setprio(1);
#pragma unroll
    for (int dt = 0; dt < 4; ++dt) {
      bf16x8 vf0 = *(const bf16x8*)(
          &Vt[bcur][dt * 2048 + vrb + (((ib + 0 + h) ^ vx) * 8)]);
      acc[dt] = __builtin_amdgcn_mfma_f32_32x32x16_bf16(pa0, vf0, acc[dt], 0, 0, 0);
      float e0 = __builtin_amdgcn_exp2f(s1[2 * dt]);
      float e1 = __builtin_amdgcn_exp2f(s1[2 * dt + 8]);
      pa2[2 * dt] = (bf16)e0;
      pa3[2 * dt] = (bf16)e1;
      bf16x8 vf1 = *(const bf16x8*)(
          &Vt[bcur][dt * 2048 + vrb + (((ib + 2 + h) ^ vx) * 8)]);
      acc[dt] = __builtin_amdgcn_mfma_f32_32x32x16_bf16(pa1, vf1, acc[dt], 0, 0, 0);
      float e2 = __builtin_amdgcn_exp2f(s1[2 * dt + 1]);
      float e3 = __builtin_amdgcn_exp2f(s1[2 * dt + 9]);
      pa2[2 * dt + 1] = (bf16)e2;
      pa3[2 * dt + 1] = (bf16)e3;
      la += (e0 + e1) + (e2 + e3);
    }

    // ---- Phase D: PV k-steps 2,3 (kvt1)
#pragma unroll
    for (int dt = 0; dt < 4; ++dt) {
      bf16x8 vf2 = *(const bf16x8*)(
          &Vt[bcur][dt * 2048 + vrb + (((ib + 4 + h) ^ vx) * 8)]);
      acc[dt] = __builtin_amdgcn_mfma_f32_32x32x16_bf16(pa2, vf2, acc[dt], 0, 0, 0);
      bf16x8 vf3 = *(const bf16x8*)(
          &Vt[bcur][dt * 2048 + vrb + (((ib + 6 + h) ^ vx) * 8)]);
      acc[dt] = __builtin_amdgcn_mfma_f32_32x32x16_bf16(pa3, vf3, acc[dt], 0, 0, 0);
    }
    __builtin_amdgcn_s_setprio(0);

    l_r += la;
    // no end-of-tile barrier: next iteration's vmcnt+barrier covers it
  }
#undef STAGE

  // ---- combine parity halves: both lanes q and q+32 hold full l[q]
  l_r += __shfl_xor(l_r, 32);

  // ---- epilogue: acc row r -> q_local = (r&3) + 8*(r>>2) + 4*h
  if (ns == 1) {
    float linv[16];
#pragma unroll
    for (int r = 0; r < 16; ++r)
      linv[r] = 1.0f / __shfl(l_r, (r & 3) + 8 * (r >> 2) + 4 * h);
#pragma unroll
    for (int dt = 0; dt < 4; ++dt)
#pragma unroll
      for (int r = 0; r < 16; ++r) {
        int row = q0 + (r & 3) + 8 * (r >> 2) + 4 * h;
        out[(size_t)(b * S_ + row) * D_ + dt * 32 + l31] = acc[dt][r] * linv[r];
      }
  } else {
#pragma unroll
    for (int dt = 0; dt < 4; ++dt)
#pragma unroll
      for (int r = 0; r < 16; ++r) {
        int row = b * S_ + q0 + (r & 3) + 8 * (r >> 2) + 4 * h;
        accP[(((size_t)seg * NR + row) << 7) + dt * 32 + l31] = (bf16)acc[dt][r];
      }
    if (lane < 32) {
      int row = b * S_ + q0 + l31;
      lP[(size_t)seg * NR + row] = l_r;
    }
  }
}

// --------------------------------------------------------------- combine pass
// Shared (zero) softmax offset => out = sum(acc)/sum(l).
__global__ __launch_bounds__(256) void combine_kernel(const bf16* __restrict__ accP,
    const float* __restrict__ lP, float* __restrict__ out, int ns) {
  const int t = blockIdx.x * 256 + threadIdx.x;      // NR*16 threads
  const int row = t >> 4, d = (t & 15) * 8;
  float L = 0.f;
  float o[8] = {0.f, 0.f, 0.f, 0.f, 0.f, 0.f, 0.f, 0.f};
  for (int i = 0; i < ns; ++i) {
    L += lP[(size_t)i * NR + row];
    bf16x8 a = *(const bf16x8*)(&accP[(((size_t)i * NR + row) << 7) + d]);
#pragma unroll
    for (int j = 0; j < 8; ++j) o[j] += (float)a[j];
  }
  float inv = 1.0f / L;
  float4 o0 = make_float4(o[0]*inv, o[1]*inv, o[2]*inv, o[3]*inv);
  float4 o1 = make_float4(o[4]*inv, o[5]*inv, o[6]*inv, o[7]*inv);
  float* op = &out[(size_t)row * 128 + d];
  *(float4*)op = o0;
  *(float4*)(op + 4) = o1;
}

// ---------------------------------------------------------------------------
extern "C" void kernel_launch(void* const* d_in, const int* in_sizes, int n_in,
                              void* d_out, int out_size, void* d_ws, size_t ws_size,
                              hipStream_t stream) {
  const float* x  = (const float*)d_in[0];
  const float* wq = (const float*)d_in[1];
  const float* wk = (const float*)d_in[2];
  const float* wv = (const float*)d_in[3];
  float* out = (float*)d_out;
  char* ws = (char*)d_ws;
  bf16* qb  = (bf16*)(ws + QB_OFF);
  bf16* kb  = (bf16*)(ws + KB_OFF);
  bf16* vtb = (bf16*)(ws + VTB_OFF);

  const size_t acc1 = (size_t)NR * D_ * 2;           // 4 MB per segment (bf16)
  const size_t l1   = (size_t)NR * 4;
  int ns = 4;                                        // 512 blocks = exactly 2/CU
  if (ws_size < ACC_OFF + 4 * (acc1 + l1)) ns = 2;
  if (ws_size < ACC_OFF + 2 * (acc1 + l1)) ns = 1;
  bf16* accP = (bf16*)(ws + ACC_OFF);
  float* lp  = (float*)(ws + ACC_OFF + (size_t)ns * acc1);

  hipLaunchKernelGGL(proj_kernel, dim3(256, 3), dim3(256), 0, stream,
                     x, wq, wk, wv, qb, kb, vtb);
  hipLaunchKernelGGL(attn_kernel, dim3(128 * ns), dim3(256), 0, stream,
                     qb, kb, vtb, out, accP, lp, ns);
  if (ns > 1)
    hipLaunchKernelGGL(combine_kernel, dim3(NR / 16), dim3(256), 0, stream,
                       accP, lp, out, ns);
}

// Round 16
// 54.782 us; speedup vs baseline: 1.0145x; 1.0145x over previous
//
#include <hip/hip_runtime.h>
#include <stdint.h>

#define B_ 4
#define S_ 4096
#define D_ 128
#define KVB 64
#define NT (S_ / KVB)
#define NR (B_ * S_)

typedef __bf16 bf16;
typedef __bf16 bf16x8 __attribute__((ext_vector_type(8)));
typedef float f32x4 __attribute__((ext_vector_type(4)));

// ws layout (bytes)
#define QB_OFF  0
#define KB_OFF  (QB_OFF + B_*S_*D_*2)
#define VTB_OFF (KB_OFF + B_*S_*D_*2)
#define ACC_OFF (VTB_OFF + B_*S_*D_*2)          // 12582912

#define GLOAD_LDS16(g, l)                                                    \
  __builtin_amdgcn_global_load_lds(                                          \
      (const __attribute__((address_space(1))) void*)(g),                    \
      (__attribute__((address_space(3))) void*)(l), 16, 0, 0)

// ------------------------------------------------- QKV projection (bf16 MFMA)
// grid (256, 3): blockIdx.y = matrix (0=Q,1=K,2=V). Each block converts its
// own W (fp32, L2-hot) into a swizzled bf16 LDS tile (16-slot XOR ->
// conflict-free writes and B-frag reads). 64 rows/block; outputs staged
// through LDS ct[], coalesced 16B stores. Q is PRE-SCALED by log2e/128 so
// attn's softmax is a bare exp2. V transposed [B][D][S], kappa-interleaved
// per 32-kv block: p = g*8+j holds kv=(j>>2)*16+g*4+(j&3).
__global__ __launch_bounds__(256) void proj_kernel(const float* __restrict__ x,
    const float* __restrict__ wq, const float* __restrict__ wk,
    const float* __restrict__ wv, bf16* __restrict__ qb, bf16* __restrict__ kb,
    bf16* __restrict__ vtb) {
  __shared__ bf16 ct[64][136];                       // 17.4 KB (C staging)
  __shared__ __align__(16) bf16 wl[128 * 128];       // 32 KB swizzled W
  const int tid  = threadIdx.x;
  const int wave = tid >> 6, lane = tid & 63;
  const int lrow = lane & 15, g = lane >> 4;
  const int m = blockIdx.y;
  const float* w = (m == 0) ? wq : (m == 1 ? wk : wv);
  const int row0b = blockIdx.x * 64;
  const int row0  = row0b + wave * 16;
  const float SC = 1.4426950408889634f / 128.0f;     // log2(e)/D

  // ---- W fp32 -> bf16 into swizzled LDS (2048 chunks of 16B, 8/thread)
#pragma unroll
  for (int it = 0; it < 8; ++it) {
    int chv = it * 256 + tid;                        // 0..2047
    int row = chv >> 4, pos = chv & 15;
    const float4* wp = (const float4*)(w + (size_t)chv * 8);
    float4 w0 = wp[0], w1 = wp[1];
    bf16x8 v;
    v[0]=(bf16)w0.x; v[1]=(bf16)w0.y; v[2]=(bf16)w0.z; v[3]=(bf16)w0.w;
    v[4]=(bf16)w1.x; v[5]=(bf16)w1.y; v[6]=(bf16)w1.z; v[7]=(bf16)w1.w;
    *(bf16x8*)(&wl[row * 128 + ((pos ^ (row & 15)) * 8)]) = v;
  }

  bf16x8 af[4];
  {
    const float* xp = x + (size_t)(row0 + lrow) * D_ + g * 8;
#pragma unroll
    for (int ks = 0; ks < 4; ++ks) {
      const float4* p4 = (const float4*)(xp + ks * 32);
      float4 a0 = p4[0], a1 = p4[1];
      bf16x8 v;
      v[0]=(bf16)a0.x; v[1]=(bf16)a0.y; v[2]=(bf16)a0.z; v[3]=(bf16)a0.w;
      v[4]=(bf16)a1.x; v[5]=(bf16)a1.y; v[6]=(bf16)a1.z; v[7]=(bf16)a1.w;
      af[ks] = v;
    }
  }
  __syncthreads();                                   // wl ready

  f32x4 acc[8];
#pragma unroll
  for (int c = 0; c < 8; ++c) acc[c] = (f32x4){0.f, 0.f, 0.f, 0.f};
#pragma unroll
  for (int c = 0; c < 8; ++c) {
#pragma unroll
    for (int ks = 0; ks < 4; ++ks) {
      bf16x8 bf = *(const bf16x8*)(
          &wl[(c * 16 + lrow) * 128 + (((ks * 4 + g) ^ lrow) * 8)]);
      acc[c] = __builtin_amdgcn_mfma_f32_16x16x32_bf16(af[ks], bf, acc[c], 0, 0, 0);
    }
  }
  const float osc = (m == 0) ? SC : 1.0f;            // pre-scale Q only
#pragma unroll
  for (int c = 0; c < 8; ++c)
#pragma unroll
    for (int r = 0; r < 4; ++r)
      ct[wave * 16 + g * 4 + r][c * 16 + lrow] = (bf16)(acc[c][r] * osc);
  __syncthreads();

  if (m < 2) {
    bf16* ob = (m == 0) ? qb : kb;
#pragma unroll
    for (int it = 0; it < 4; ++it) {
      int chunk = it * 256 + tid;
      int row = chunk >> 4, pos = chunk & 15;
      *(bf16x8*)(ob + (size_t)(row0b + row) * D_ + pos * 8) =
          *(const bf16x8*)(&ct[row][pos * 8]);
    }
  } else {
    const int b = row0b / S_;
    const int sb = row0b & (S_ - 1);
#pragma unroll
    for (int it = 0; it < 4; ++it) {
      int ci = it * 256 + tid;
      int e = ci >> 3, hc = ci & 7;
      int h = hc >> 2, gg = hc & 3;
      bf16x8 v;
#pragma unroll
      for (int j = 0; j < 8; ++j)
        v[j] = ct[h * 32 + ((j >> 2) * 16 + gg * 4 + (j & 3))][e];
      *(bf16x8*)(vtb + (size_t)(b * D_ + e) * S_ + sb + h * 32 + gg * 8) = v;
    }
  }
}

// ------------------------------------------------------------ flash attention
// R14 configuration (proven best, 54.7us total): KVB=64, 1 vmcnt(0)+barrier
// per tile, 2-deep LDS buffers, 4 waves x 32 q-rows. Softmax of score-group
// ti-1 software-interleaved into the QK MFMA stream of group ti (exp2 burst
// hides under MFMA issue). setprio only around the PV cluster (T5, m191).
// Swapped QK^T keeps P lane-local; kappa-permuted PV consumes packed P from
// registers. Softmax: p = exp2(s) (Q pre-scaled; offsets cancel in combine).
__global__ __launch_bounds__(256, 2) void attn_kernel(const bf16* __restrict__ qb,
    const bf16* __restrict__ kb, const bf16* __restrict__ vtb,
    float* __restrict__ out, bf16* __restrict__ accP, float* __restrict__ lP,
    int ns) {
  __shared__ __align__(16) bf16 Kt[2][KVB * 128];    // 2 x 16KB
  __shared__ __align__(16) bf16 Vt[2][128 * KVB];    // 2 x 16KB

  const int tid  = threadIdx.x;
  const int wave = tid >> 6, lane = tid & 63;
  const int lrow = lane & 15, g = lane >> 4;

  // bijective XCD swizzle (gridDim.x % 8 == 0 for ns in {1,2,4})
  const int nwg = gridDim.x;
  int gid = blockIdx.x;
  if ((nwg & 7) == 0) gid = (gid & 7) * (nwg >> 3) + (gid >> 3);
  const int qp  = gid & 127;                         // q-part 0..127
  const int seg = gid >> 7;                          // 0..ns-1
  const int b   = qp >> 5;
  const int q0  = (qp & 31) * 128 + wave * 32;       // wave's 32 q-rows

  // uneven tile ranges: first (NT%ns) segs get one extra tile
  const int base = NT / ns, ext = NT % ns;
  const int cnt  = base + (seg < ext);
  const int t0   = seg * base + (seg < ext ? seg : ext);
  const int tend = t0 + cnt;

  // ---- precomputed staging offsets (lane-constant across tiles)
  int koff[4], voff[4], kd[4];
#pragma unroll
  for (int it = 0; it < 4; ++it) {
    int ci = (wave * 4 + it) * 64 + lane;            // 0..1023
    int krow = ci >> 4, kch = (ci & 15) ^ (krow & 15);
    koff[it] = krow * D_ + kch * 8;
    int d = ci >> 3, vch = (ci & 7) ^ (d & 7);
    voff[it] = d * S_ + vch * 8;
    kd[it] = (wave * 4 + it) * 512;                  // uniform dest (bf16 idx)
  }

  bf16x8 qf[2][4];
#pragma unroll
  for (int a = 0; a < 2; ++a) {
    const bf16* qp_ = qb + (size_t)(b * S_ + q0 + a * 16 + lrow) * D_ + g * 8;
#pragma unroll
    for (int ks = 0; ks < 4; ++ks) qf[a][ks] = *(const bf16x8*)(qp_ + ks * 32);
  }

  f32x4 acc[2][8];
#pragma unroll
  for (int a = 0; a < 2; ++a)
#pragma unroll
    for (int c = 0; c < 8; ++c) acc[a][c] = (f32x4){0.f, 0.f, 0.f, 0.f};
  float l_r[2] = {0.f, 0.f};                         // per-lane partial sums

  const bf16* kbase = kb + (size_t)b * S_ * D_;
  const bf16* vbase = vtb + (size_t)b * D_ * S_;

#define STAGE(tt, buf)                                                       \
  { const bf16* kp_ = kbase + (size_t)(tt) * KVB * D_;                       \
    const bf16* vp_ = vbase + (tt) * KVB;                                    \
    GLOAD_LDS16(kp_ + koff[0], &Kt[buf][kd[0]]);                             \
    GLOAD_LDS16(kp_ + koff[1], &Kt[buf][kd[1]]);                             \
    GLOAD_LDS16(kp_ + koff[2], &Kt[buf][kd[2]]);                             \
    GLOAD_LDS16(kp_ + koff[3], &Kt[buf][kd[3]]);                             \
    GLOAD_LDS16(vp_ + voff[0], &Vt[buf][kd[0]]);                             \
    GLOAD_LDS16(vp_ + voff[1], &Vt[buf][kd[1]]);                             \
    GLOAD_LDS16(vp_ + voff[2], &Vt[buf][kd[2]]);                             \
    GLOAD_LDS16(vp_ + voff[3], &Vt[buf][kd[3]]); }

  STAGE(t0, 0);                                      // prologue: tile t0

  for (int t = t0; t < tend; ++t) {
    const int bcur = (t - t0) & 1;
    // wait own tile-t loads (issued a full compute phase ago), then barrier:
    // all waves' tile-t data in LDS AND buffer bcur^1 free for restaging.
    asm volatile("s_waitcnt vmcnt(0)\n\ts_barrier" ::: "memory");
    if (t + 1 < tend) STAGE(t + 1, bcur ^ 1);

    // ---- S^T = K Q with interleaved softmax: SM(ti-1) rides under QK(ti).
    // lane holds S[q=(lane&15)+16a][kv = ti*16 + g*4 + r]
    f32x4 s[2][4];
#pragma unroll
    for (int a = 0; a < 2; ++a)
#pragma unroll
      for (int ti = 0; ti < 4; ++ti) s[a][ti] = (f32x4){0.f, 0.f, 0.f, 0.f};
    float ts[2] = {0.f, 0.f};
    bf16x8 pa[2][2];
#pragma unroll
    for (int ti = 0; ti < 4; ++ti) {
#pragma unroll
      for (int ks = 0; ks < 4; ++ks) {
        const int row = ti * 16 + lrow;
        bf16x8 kf = *(const bf16x8*)(
            &Kt[bcur][row * 128 + (((ks * 4 + g) ^ lrow) * 8)]);
        s[0][ti] = __builtin_amdgcn_mfma_f32_16x16x32_bf16(kf, qf[0][ks], s[0][ti], 0, 0, 0);
        s[1][ti] = __builtin_amdgcn_mfma_f32_16x16x32_bf16(kf, qf[1][ks], s[1][ti], 0, 0, 0);
      }
      if (ti >= 1) {
        const int j = ti - 1;                        // softmax group j done
#pragma unroll
        for (int a = 0; a < 2; ++a)
#pragma unroll
          for (int r = 0; r < 4; ++r) {
            float e = __builtin_amdgcn_exp2f(s[a][j][r]);
            ts[a] += e;
            pa[a][j >> 1][(j & 1) * 4 + r] = (bf16)e;
          }
      }
    }
#pragma unroll
    for (int a = 0; a < 2; ++a)                      // SM(3)
#pragma unroll
      for (int r = 0; r < 4; ++r) {
        float e = __builtin_amdgcn_exp2f(s[a][3][r]);
        ts[a] += e;
        pa[a][1][4 + r] = (bf16)e;
      }
    l_r[0] += ts[0];
    l_r[1] += ts[1];

    // ---- O += P V  (kappa order matches packed P)
    __builtin_amdgcn_s_setprio(1);
#pragma unroll
    for (int c = 0; c < 8; ++c) {
      const int d = c * 16 + lrow;
#pragma unroll
      for (int bb = 0; bb < 2; ++bb) {
        bf16x8 vf = *(const bf16x8*)(
            &Vt[bcur][d * KVB + (((bb * 4 + g) ^ (d & 7)) * 8)]);
        acc[0][c] = __builtin_amdgcn_mfma_f32_16x16x32_bf16(pa[0][bb], vf, acc[0][c], 0, 0, 0);
        acc[1][c] = __builtin_amdgcn_mfma_f32_16x16x32_bf16(pa[1][bb], vf, acc[1][c], 0, 0, 0);
      }
    }
    __builtin_amdgcn_s_setprio(0);
    // no end-of-tile barrier: next iteration's vmcnt+barrier covers it
  }
#undef STAGE

  // ---- final cross-lane l reduction (once, not per tile)
#pragma unroll
  for (int a = 0; a < 2; ++a) {
    l_r[a] += __shfl_xor(l_r[a], 16);
    l_r[a] += __shfl_xor(l_r[a], 32);
  }

  // ---- epilogue
  if (ns == 1) {
#pragma unroll
    for (int a = 0; a < 2; ++a) {
      float linv[4];
#pragma unroll
      for (int r = 0; r < 4; ++r) linv[r] = 1.0f / __shfl(l_r[a], g * 4 + r);
#pragma unroll
      for (int c = 0; c < 8; ++c)
#pragma unroll
        for (int r = 0; r < 4; ++r) {
          int row = q0 + a * 16 + g * 4 + r;
          out[(size_t)(b * S_ + row) * D_ + c * 16 + lrow] = acc[a][c][r] * linv[r];
        }
    }
  } else {
#pragma unroll
    for (int a = 0; a < 2; ++a) {
#pragma unroll
      for (int c = 0; c < 8; ++c)
#pragma unroll
        for (int r = 0; r < 4; ++r) {
          int row = b * S_ + q0 + a * 16 + g * 4 + r;
          accP[(((size_t)seg * NR + row) << 7) + c * 16 + lrow] = (bf16)acc[a][c][r];
        }
      if (g == 0) {
        int row = b * S_ + q0 + a * 16 + lrow;
        lP[(size_t)seg * NR + row] = l_r[a];
      }
    }
  }
}

// --------------------------------------------------------------- combine pass
// Shared (zero) softmax offset => out = sum(acc)/sum(l).
__global__ __launch_bounds__(256) void combine_kernel(const bf16* __restrict__ accP,
    const float* __restrict__ lP, float* __restrict__ out, int ns) {
  const int t = blockIdx.x * 256 + threadIdx.x;      // NR*16 threads
  const int row = t >> 4, d = (t & 15) * 8;
  float L = 0.f;
  float o[8] = {0.f, 0.f, 0.f, 0.f, 0.f, 0.f, 0.f, 0.f};
  for (int i = 0; i < ns; ++i) {
    L += lP[(size_t)i * NR + row];
    bf16x8 a = *(const bf16x8*)(&accP[(((size_t)i * NR + row) << 7) + d]);
#pragma unroll
    for (int j = 0; j < 8; ++j) o[j] += (float)a[j];
  }
  float inv = 1.0f / L;
  float4 o0 = make_float4(o[0]*inv, o[1]*inv, o[2]*inv, o[3]*inv);
  float4 o1 = make_float4(o[4]*inv, o[5]*inv, o[6]*inv, o[7]*inv);
  float* op = &out[(size_t)row * 128 + d];
  *(float4*)op = o0;
  *(float4*)(op + 4) = o1;
}

// ---------------------------------------------------------------------------
extern "C" void kernel_launch(void* const* d_in, const int* in_sizes, int n_in,
                              void* d_out, int out_size, void* d_ws, size_t ws_size,
                              hipStream_t stream) {
  const float* x  = (const float*)d_in[0];
  const float* wq = (const float*)d_in[1];
  const float* wk = (const float*)d_in[2];
  const float* wv = (const float*)d_in[3];
  float* out = (float*)d_out;
  char* ws = (char*)d_ws;
  bf16* qb  = (bf16*)(ws + QB_OFF);
  bf16* kb  = (bf16*)(ws + KB_OFF);
  bf16* vtb = (bf16*)(ws + VTB_OFF);

  const size_t acc1 = (size_t)NR * D_ * 2;           // 4 MB per segment (bf16)
  const size_t l1   = (size_t)NR * 4;
  int ns = 4;                                        // 512 blocks = exactly 2/CU
  if (ws_size < ACC_OFF + 4 * (acc1 + l1)) ns = 2;
  if (ws_size < ACC_OFF + 2 * (acc1 + l1)) ns = 1;
  bf16* accP = (bf16*)(ws + ACC_OFF);
  float* lp  = (float*)(ws + ACC_OFF + (size_t)ns * acc1);

  hipLaunchKernelGGL(proj_kernel, dim3(256, 3), dim3(256), 0, stream,
                     x, wq, wk, wv, qb, kb, vtb);
  hipLaunchKernelGGL(attn_kernel, dim3(128 * ns), dim3(256), 0, stream,
                     qb, kb, vtb, out, accP, lp, ns);
  if (ns > 1)
    hipLaunchKernelGGL(combine_kernel, dim3(NR / 16), dim3(256), 0, stream,
                       accP, lp, out, ns);
}